// Round 1
// baseline (1889.753 us; speedup 1.0000x reference)
//
#include <hip/hip_runtime.h>

typedef unsigned short u16;
typedef __attribute__((ext_vector_type(8))) short bfrag8;     // 8 bf16 = 4 VGPR (MFMA A/B frag)
typedef __attribute__((ext_vector_type(4))) float fvec4;      // MFMA C/D frag
typedef __attribute__((ext_vector_type(4))) unsigned short usvec4;

// ---- problem constants ----
#define Bc   16
#define Nn   10000
#define Rr   10
#define Ss   1000
#define Gg   4
#define SP   1024      // K-padded S
#define NPAD 10048     // padded row count for inpT (r*1000 + t, t<1024 max = 10023)

__device__ __forceinline__ float bf2f(u16 u) {
  union { unsigned int i; float f; } x; x.i = ((unsigned int)u) << 16; return x.f;
}
__device__ __forceinline__ u16 f2bf(float f) {
  unsigned int x = __float_as_uint(f);
  unsigned int r = x + 0x7FFFu + ((x >> 16) & 1u);   // RNE; no NaNs in this workload
  return (u16)(r >> 16);
}

// ---------------- K0: weight prep (Wt bf16 transposed [p][g][e][d], a1w bf16) ----------------
__global__ __launch_bounds__(256) void prep_weights_kernel(
    const float* __restrict__ Wu, const float* __restrict__ Wr, const float* __restrict__ Wc,
    const float* __restrict__ a1u, const float* __restrict__ a1r, const float* __restrict__ a1c,
    u16* __restrict__ Wt, u16* __restrict__ a1wb)
{
  int idx = blockIdx.x * 256 + threadIdx.x;
  if (idx < 73728) {                       // 3*4*64*96
    int p = idx / 24576, rem = idx % 24576;
    int g = rem / 6144, r2 = rem % 6144;
    int e = r2 / 96, dd = r2 % 96;
    const float* W = (p == 0) ? Wu : (p == 1) ? Wr : Wc;   // W[g][d][e]
    Wt[idx] = f2bf(W[(g * 96 + dd) * 64 + e]);
  } else if (idx < 73728 + 49536) {        // 3*258*64
    int j = idx - 73728;
    int p = j / 16512, k = j % 16512;
    const float* s = (p == 0) ? a1u : (p == 1) ? a1r : a1c;
    a1wb[j] = f2bf(s[k]);
  }
}

// ---------------- K1: row sums -> deg^-0.5 ----------------
__global__ __launch_bounds__(256) void rowsum_kernel(const float* __restrict__ A,
                                                     float* __restrict__ dis)
{
  int wid = threadIdx.x >> 6, lane = threadIdx.x & 63;
  int row = blockIdx.x * 4 + wid;          // 40000 rows
  const float* ap = A + (size_t)row * 1000;
  float s = 0.f;
  for (int i = lane; i < 250; i += 64) {
    float4 v = *(const float4*)(ap + i * 4);
    s += (v.x + v.y) + (v.z + v.w);
  }
  #pragma unroll
  for (int off = 32; off >= 1; off >>= 1) s += __shfl_xor(s, off);
  if (lane == 0) dis[row] = rsqrtf(fmaxf(s, 1e-5f));
}

// ---------------- K2: build An (bf16, K padded to 1024 with zeros) ----------------
__global__ __launch_bounds__(256) void build_an_kernel(const float* __restrict__ A,
                                                       const float* __restrict__ dis,
                                                       u16* __restrict__ An)
{
  int rowid = blockIdx.x;                  // (g*10+r)*1000 + s, 0..39999
  int gr = rowid / 1000, s = rowid % 1000;
  float ds = dis[rowid];
  const float* ap = A + (size_t)rowid * 1000;
  u16* anp = An + (size_t)rowid * SP;
  int t4 = threadIdx.x * 4;                // 0..1020
  if (t4 < 1000) {
    float4 a4 = *(const float4*)(ap + t4);
    float4 d4 = *(const float4*)(dis + gr * 1000 + t4);
    float v0 = ds * d4.x * (a4.x + ((t4 + 0) == s ? 1.f : 0.f));
    float v1 = ds * d4.y * (a4.y + ((t4 + 1) == s ? 1.f : 0.f));
    float v2 = ds * d4.z * (a4.z + ((t4 + 2) == s ? 1.f : 0.f));
    float v3 = ds * d4.w * (a4.w + ((t4 + 3) == s ? 1.f : 0.f));
    usvec4 o = {f2bf(v0), f2bf(v1), f2bf(v2), f2bf(v3)};
    *(usvec4*)(anp + t4) = o;
  } else {
    usvec4 o = {0, 0, 0, 0};
    *(usvec4*)(anp + t4) = o;              // zero pad cols 1000..1023
  }
}

// ---------------- K3: inp prep, transposed d-major: inpT[b][d 0..95][n 0..10047] ----------------
__global__ __launch_bounds__(256) void prep_inpT_kernel(const float* __restrict__ x_t,
                                                        const float* __restrict__ h_prev,
                                                        u16* __restrict__ inpT)
{
  int b = blockIdx.y, n0 = blockIdx.x * 64;   // 157 x-blocks cover 10048 rows
  __shared__ float t[64][97];
  for (int idx = threadIdx.x; idx < 2048; idx += 256) {       // x_t part: 64 x 32
    int ni = idx >> 5, d = idx & 31;
    int n = n0 + ni;
    t[ni][d] = (n < Nn) ? x_t[(size_t)(b * Nn + n) * 32 + d] : 0.f;
  }
  for (int idx = threadIdx.x; idx < 4096; idx += 256) {       // h_prev part: 64 x 64
    int ni = idx >> 6, d = idx & 63;
    int n = n0 + ni;
    t[ni][32 + d] = (n < Nn) ? h_prev[(size_t)(b * Nn + n) * 64 + d] : 0.f;
  }
  __syncthreads();
  for (int idx = threadIdx.x; idx < 6144; idx += 256) {       // 96 x 64 transposed store
    int d = idx >> 6, ni = idx & 63;
    inpT[(size_t)b * (96 * NPAD) + (size_t)d * NPAD + n0 + ni] = f2bf(t[ni][d]);
  }
}

// ---------------- K4: fused GEMM  outs_p = relu( (An @ inp) @ W_p ) ----------------
// grid (8 mtiles, 16 b, 40 gr), block 256 (4 waves, wave = 32 rows x 96 cols)
template <int NPROJ>
__global__ __launch_bounds__(256) void gemm_pass_kernel(
    const u16* __restrict__ An,     // [40][1000][1024] bf16
    const u16* __restrict__ inpT,   // [16][96][10048]  bf16
    const u16* __restrict__ Wt,     // [NPROJ][4][64][96] bf16 (W^T per g)
    u16* __restrict__ outs0, u16* __restrict__ outs1)
{
  constexpr int BT_OFF = 128 * 40;  // 5120 ushorts
  __shared__ __align__(16) u16 lds_main[12288];          // max(A 128x40 + B 96x40, Ai 128x96)
  __shared__ __align__(16) u16 lds_w[NPROJ * 6144];

  const int tid = threadIdx.x;
  const int lane = tid & 63, wid = tid >> 6;
  const int mt = blockIdx.x, b = blockIdx.y, gr = blockIdx.z;
  const int g = gr / Rr, r = gr % Rr;
  const int m0 = mt * 128;
  const int wrow0 = wid * 32;
  const int lr = lane & 15, lk = (lane >> 4) << 3;       // frag row-in-16, k-offset

  for (int i = tid; i < NPROJ * 768; i += 256) {         // stage W^T for this g
    int p = i / 768, idx = (i % 768) * 8;
    *(bfrag8*)&lds_w[p * 6144 + idx] = *(const bfrag8*)&Wt[(p * Gg + g) * 6144 + idx];
  }

  const u16* Ap = An + (size_t)gr * (Ss * SP);
  const u16* Bp = inpT + (size_t)b * (96 * NPAD) + r * Ss;

  fvec4 acc[2][6];
  #pragma unroll
  for (int i = 0; i < 2; ++i)
    #pragma unroll
    for (int j = 0; j < 6; ++j) acc[i][j] = (fvec4){0.f, 0.f, 0.f, 0.f};

  #pragma unroll 1
  for (int kk = 0; kk < SP; kk += 32) {
    __syncthreads();
    // stage An tile 128x32 (rows >= 1000 -> zero)
    #pragma unroll
    for (int s2 = 0; s2 < 2; ++s2) {
      int seg = tid + (s2 << 8);
      int row = seg >> 2, kl = (seg & 3) << 3;
      int srow = m0 + row;
      bfrag8 v = (bfrag8){0, 0, 0, 0, 0, 0, 0, 0};
      if (srow < Ss) v = *(const bfrag8*)(Ap + (size_t)srow * SP + kk + kl);
      *(bfrag8*)&lds_main[row * 40 + kl] = v;
    }
    // stage inp^T tile 96x32
    {
      int d = tid >> 2, tl = (tid & 3) << 3;
      *(bfrag8*)&lds_main[BT_OFF + d * 40 + tl] = *(const bfrag8*)(Bp + (size_t)d * NPAD + kk + tl);
      if (tid < 128) {
        int seg = 256 + tid;
        int d2 = seg >> 2, t2 = (seg & 3) << 3;
        *(bfrag8*)&lds_main[BT_OFF + d2 * 40 + t2] = *(const bfrag8*)(Bp + (size_t)d2 * NPAD + kk + t2);
      }
    }
    __syncthreads();
    bfrag8 af0 = *(const bfrag8*)&lds_main[(wrow0 + lr) * 40 + lk];
    bfrag8 af1 = *(const bfrag8*)&lds_main[(wrow0 + 16 + lr) * 40 + lk];
    #pragma unroll
    for (int nf = 0; nf < 6; ++nf) {
      bfrag8 bfr = *(const bfrag8*)&lds_main[BT_OFF + (nf * 16 + lr) * 40 + lk];
      acc[0][nf] = __builtin_amdgcn_mfma_f32_16x16x32_bf16(af0, bfr, acc[0][nf], 0, 0, 0);
      acc[1][nf] = __builtin_amdgcn_mfma_f32_16x16x32_bf16(af1, bfr, acc[1][nf], 0, 0, 0);
    }
  }

  // epilogue stage 1: Ai (f32 acc) -> LDS bf16 [128][96]
  __syncthreads();
  #pragma unroll
  for (int mf = 0; mf < 2; ++mf)
    #pragma unroll
    for (int nf = 0; nf < 6; ++nf)
      #pragma unroll
      for (int j = 0; j < 4; ++j) {
        int row = wrow0 + mf * 16 + ((lane >> 4) << 2) + j;
        lds_main[row * 96 + nf * 16 + lr] = f2bf(acc[mf][nf][j]);
      }
  __syncthreads();

  // epilogue stage 2: per proj, [32x96] @ [96x64] + relu + store
  const int obase = ((g * Bc + b) * Nn + r * Ss) * 64;
  #pragma unroll
  for (int p = 0; p < NPROJ; ++p) {
    fvec4 acc2[2][4];
    #pragma unroll
    for (int i = 0; i < 2; ++i)
      #pragma unroll
      for (int j = 0; j < 4; ++j) acc2[i][j] = (fvec4){0.f, 0.f, 0.f, 0.f};
    #pragma unroll
    for (int dk = 0; dk < 96; dk += 32) {
      bfrag8 x0 = *(const bfrag8*)&lds_main[(wrow0 + lr) * 96 + dk + lk];
      bfrag8 x1 = *(const bfrag8*)&lds_main[(wrow0 + 16 + lr) * 96 + dk + lk];
      #pragma unroll
      for (int ef = 0; ef < 4; ++ef) {
        bfrag8 wv = *(const bfrag8*)&lds_w[p * 6144 + (ef * 16 + lr) * 96 + dk + lk];
        acc2[0][ef] = __builtin_amdgcn_mfma_f32_16x16x32_bf16(x0, wv, acc2[0][ef], 0, 0, 0);
        acc2[1][ef] = __builtin_amdgcn_mfma_f32_16x16x32_bf16(x1, wv, acc2[1][ef], 0, 0, 0);
      }
    }
    u16* op = (p == 0) ? outs0 : outs1;
    #pragma unroll
    for (int mf = 0; mf < 2; ++mf)
      #pragma unroll
      for (int ef = 0; ef < 4; ++ef)
        #pragma unroll
        for (int j = 0; j < 4; ++j) {
          int srow = m0 + wrow0 + mf * 16 + ((lane >> 4) << 2) + j;
          if (srow < Ss) {
            float v = fmaxf(acc2[mf][ef][j], 0.f);
            op[obase + srow * 64 + ef * 16 + lr] = f2bf(v);
          }
        }
  }
}

// ---------------- K5: attention combine (MODE 0=U sigmoid, 1=R cand, 2=C final) ----------------
template <int MODE>
__global__ __launch_bounds__(256) void attn_kernel(
    const u16* __restrict__ outs,      // [4][16][10000][64] bf16 (relu'd)
    const float* __restrict__ rs,      // [16][10000][2]
    const u16* __restrict__ a1wb,      // [258][64] bf16
    const float* __restrict__ a1b, const float* __restrict__ a2w, const float* __restrict__ a2b,
    const float* __restrict__ h_prev, const float* __restrict__ u_sig_in,
    float* __restrict__ usig_out, u16* __restrict__ candh_out, float* __restrict__ out_final)
{
  __shared__ u16 a1w_lds[16512];
  __shared__ float Hl[4][256];
  const int tid = threadIdx.x, lane = tid & 63, wid = tid >> 6;
  for (int s = tid; s < 2064; s += 256)
    *(bfrag8*)&a1w_lds[s * 8] = *(const bfrag8*)&a1wb[s * 8];
  __syncthreads();

  const float a1b_l = a1b[lane];
  float a2w_l[4];
  #pragma unroll
  for (int g2 = 0; g2 < 4; ++g2) a2w_l[g2] = a2w[lane * 4 + g2];
  const float b0 = a2b[0], b1 = a2b[1], b2 = a2b[2], b3 = a2b[3];

  const int nwaves = gridDim.x * 4;
  for (int row = blockIdx.x * 4 + wid; row < Bc * Nn; row += nwaves) {
    float hg[4];
    #pragma unroll
    for (int g2 = 0; g2 < 4; ++g2) {
      hg[g2] = bf2f(outs[((size_t)g2 * Bc * Nn + row) * 64 + lane]);
      Hl[wid][g2 * 64 + lane] = hg[g2];
    }
    float z = a1b_l;
    #pragma unroll 1
    for (int k = 0; k < 256; k += 8) {
      #pragma unroll
      for (int j = 0; j < 8; ++j)
        z = fmaf(Hl[wid][k + j], bf2f(a1w_lds[(k + j) * 64 + lane]), z);
    }
    float r0 = rs[row * 2], r1 = rs[row * 2 + 1];
    z = fmaf(r0, bf2f(a1w_lds[256 * 64 + lane]), z);
    z = fmaf(r1, bf2f(a1w_lds[257 * 64 + lane]), z);
    z = fmaxf(z, 0.f);
    float p0 = z * a2w_l[0], p1 = z * a2w_l[1], p2 = z * a2w_l[2], p3 = z * a2w_l[3];
    #pragma unroll
    for (int off = 32; off >= 1; off >>= 1) {
      p0 += __shfl_xor(p0, off); p1 += __shfl_xor(p1, off);
      p2 += __shfl_xor(p2, off); p3 += __shfl_xor(p3, off);
    }
    p0 += b0; p1 += b1; p2 += b2; p3 += b3;
    float m = fmaxf(fmaxf(p0, p1), fmaxf(p2, p3));
    float e0 = __expf(p0 - m), e1 = __expf(p1 - m), e2 = __expf(p2 - m), e3 = __expf(p3 - m);
    if (r1 > 0.5f) { e0 *= 1.1f; e1 *= 1.1f; e2 *= 1.1f; e3 *= 2.0f; }   // alpha*(1+bias), renorm below
    float inv = 1.f / (e0 + e1 + e2 + e3);
    float comb = (e0 * hg[0] + e1 * hg[1] + e2 * hg[2] + e3 * hg[3]) * inv;

    if (MODE == 0) {
      usig_out[(size_t)row * 64 + lane] = 1.f / (1.f + __expf(-comb));
    } else if (MODE == 1) {
      candh_out[(size_t)row * 64 + lane] = f2bf(comb * h_prev[(size_t)row * 64 + lane]);
    } else {
      float u = u_sig_in[(size_t)row * 64 + lane];
      float hp = h_prev[(size_t)row * 64 + lane];
      out_final[(size_t)row * 64 + lane] = u * tanhf(comb) + (1.f - u) * hp;
    }
  }
}

// ---------------- K6: transpose candh [b][n][e] -> inpT rows d=32..95 ----------------
__global__ __launch_bounds__(256) void transpose_cand_kernel(const u16* __restrict__ candh,
                                                             u16* __restrict__ inpT)
{
  int b = blockIdx.y, n0 = blockIdx.x * 64;
  __shared__ float t[64][65];
  for (int idx = threadIdx.x; idx < 4096; idx += 256) {
    int ni = idx >> 6, e = idx & 63;
    int n = n0 + ni;
    t[ni][e] = (n < Nn) ? bf2f(candh[(size_t)(b * Nn + n) * 64 + e]) : 0.f;
  }
  __syncthreads();
  for (int idx = threadIdx.x; idx < 4096; idx += 256) {
    int e = idx >> 6, ni = idx & 63;
    inpT[(size_t)b * (96 * NPAD) + (size_t)(32 + e) * NPAD + n0 + ni] = f2bf(t[ni][e]);
  }
}

// ---------------- host ----------------
extern "C" void kernel_launch(void* const* d_in, const int* in_sizes, int n_in,
                              void* d_out, int out_size, void* d_ws, size_t ws_size,
                              hipStream_t stream) {
  (void)in_sizes; (void)n_in; (void)out_size; (void)ws_size;
  const float* x_t    = (const float*)d_in[0];
  const float* h_prev = (const float*)d_in[1];
  const float* A      = (const float*)d_in[2];
  const float* rs     = (const float*)d_in[3];
  const float* W_u    = (const float*)d_in[4];
  const float* a1w_u  = (const float*)d_in[5];
  const float* a1b_u  = (const float*)d_in[6];
  const float* a2w_u  = (const float*)d_in[7];
  const float* a2b_u  = (const float*)d_in[8];
  const float* W_r    = (const float*)d_in[9];
  const float* a1w_r  = (const float*)d_in[10];
  const float* a1b_r  = (const float*)d_in[11];
  const float* a2w_r  = (const float*)d_in[12];
  const float* a2b_r  = (const float*)d_in[13];
  const float* W_c    = (const float*)d_in[14];
  const float* a1w_c  = (const float*)d_in[15];
  const float* a1b_c  = (const float*)d_in[16];
  const float* a2w_c  = (const float*)d_in[17];
  const float* a2b_c  = (const float*)d_in[18];
  float* out = (float*)d_out;

  char* ws = (char*)d_ws;
  // ws layout (bytes)
  const size_t AN_OFF    = 0;                                  // 40*1000*1024 bf16 = 81,920,000
  const size_t DIS_OFF   = 81920000;                           // 40000 f32
  const size_t INPT_OFF  = 82080000;                           // 16*96*10048 bf16 = 30,867,456
  const size_t OUTSU_OFF = 112947456;                          // 40,960,000 bf16 -> 81,920,000 B
  const size_t OUTSR_OFF = 194867456;
  const size_t USIG_OFF  = 276787456;                          // 10,240,000 f32
  const size_t CANDH_OFF = 317747456;                          // 10,240,000 bf16
  const size_t WT_OFF    = 338227456;                          // 73,728 bf16
  const size_t A1WB_OFF  = 338374912;                          // 49,536 bf16

  u16* An    = (u16*)(ws + AN_OFF);
  float* dis = (float*)(ws + DIS_OFF);
  u16* inpT  = (u16*)(ws + INPT_OFF);
  u16* outsU = (u16*)(ws + OUTSU_OFF);
  u16* outsR = (u16*)(ws + OUTSR_OFF);
  u16* outsC = outsU;                                          // reuse after attn_U
  float* usig = (float*)(ws + USIG_OFF);
  u16* candh = (u16*)(ws + CANDH_OFF);
  u16* Wt    = (u16*)(ws + WT_OFF);
  u16* a1wb  = (u16*)(ws + A1WB_OFF);

  prep_weights_kernel<<<482, 256, 0, stream>>>(W_u, W_r, W_c, a1w_u, a1w_r, a1w_c, Wt, a1wb);
  rowsum_kernel<<<10000, 256, 0, stream>>>(A, dis);
  build_an_kernel<<<40000, 256, 0, stream>>>(A, dis, An);
  prep_inpT_kernel<<<dim3(157, 16), 256, 0, stream>>>(x_t, h_prev, inpT);

  gemm_pass_kernel<2><<<dim3(8, 16, 40), 256, 0, stream>>>(An, inpT, Wt, outsU, outsR);

  attn_kernel<0><<<2048, 256, 0, stream>>>(outsU, rs, a1wb, a1b_u, a2w_u, a2b_u,
                                           nullptr, nullptr, usig, nullptr, nullptr);
  attn_kernel<1><<<2048, 256, 0, stream>>>(outsR, rs, a1wb + 16512, a1b_r, a2w_r, a2b_r,
                                           h_prev, nullptr, nullptr, candh, nullptr);
  transpose_cand_kernel<<<dim3(157, 16), 256, 0, stream>>>(candh, inpT);

  gemm_pass_kernel<1><<<dim3(8, 16, 40), 256, 0, stream>>>(An, inpT, Wt + 2 * 24576, outsC, nullptr);

  attn_kernel<2><<<2048, 256, 0, stream>>>(outsC, rs, a1wb + 2 * 16512, a1b_c, a2w_c, a2b_c,
                                           h_prev, usig, nullptr, nullptr, out);
}

// Round 2
// 1156.125 us; speedup vs baseline: 1.6346x; 1.6346x over previous
//
#include <hip/hip_runtime.h>

typedef unsigned short u16;
typedef __attribute__((ext_vector_type(8))) short bfrag8;     // 8 bf16 = 4 VGPR (MFMA A/B frag)
typedef __attribute__((ext_vector_type(4))) float fvec4;      // MFMA C/D frag
typedef __attribute__((ext_vector_type(4))) unsigned short usvec4;

// ---- problem constants ----
#define Bc   16
#define Nn   10000
#define Rr   10
#define Ss   1000
#define Gg   4
#define SP   1024      // K-padded S
#define NPAD 10048     // padded row count for inpT

__device__ __forceinline__ float bf2f(u16 u) {
  union { unsigned int i; float f; } x; x.i = ((unsigned int)u) << 16; return x.f;
}
__device__ __forceinline__ u16 f2bf(float f) {
  unsigned int x = __float_as_uint(f);
  unsigned int r = x + 0x7FFFu + ((x >> 16) & 1u);   // RNE; no NaNs in this workload
  return (u16)(r >> 16);
}

// ---------------- K0: weight prep ----------------
__global__ __launch_bounds__(256) void prep_weights_kernel(
    const float* __restrict__ Wu, const float* __restrict__ Wr, const float* __restrict__ Wc,
    const float* __restrict__ a1u, const float* __restrict__ a1r, const float* __restrict__ a1c,
    u16* __restrict__ Wt, u16* __restrict__ a1wb)
{
  int idx = blockIdx.x * 256 + threadIdx.x;
  if (idx < 73728) {                       // 3*4*64*96
    int p = idx / 24576, rem = idx % 24576;
    int g = rem / 6144, r2 = rem % 6144;
    int e = r2 / 96, dd = r2 % 96;
    const float* W = (p == 0) ? Wu : (p == 1) ? Wr : Wc;   // W[g][d][e]
    Wt[idx] = f2bf(W[(g * 96 + dd) * 64 + e]);
  } else if (idx < 73728 + 49536) {        // 3*258*64
    int j = idx - 73728;
    int p = j / 16512, k = j % 16512;
    const float* s = (p == 0) ? a1u : (p == 1) ? a1r : a1c;
    a1wb[j] = f2bf(s[k]);
  }
}

// ---------------- K1: row sums -> deg^-0.5 ----------------
__global__ __launch_bounds__(256) void rowsum_kernel(const float* __restrict__ A,
                                                     float* __restrict__ dis)
{
  int wid = threadIdx.x >> 6, lane = threadIdx.x & 63;
  int row = blockIdx.x * 4 + wid;          // 40000 rows
  const float* ap = A + (size_t)row * 1000;
  float s = 0.f;
  for (int i = lane; i < 250; i += 64) {
    float4 v = *(const float4*)(ap + i * 4);
    s += (v.x + v.y) + (v.z + v.w);
  }
  #pragma unroll
  for (int off = 32; off >= 1; off >>= 1) s += __shfl_xor(s, off);
  if (lane == 0) dis[row] = rsqrtf(fmaxf(s, 1e-5f));
}

// ---------------- K2: build An (bf16, K padded to 1024 with zeros) ----------------
__global__ __launch_bounds__(256) void build_an_kernel(const float* __restrict__ A,
                                                       const float* __restrict__ dis,
                                                       u16* __restrict__ An)
{
  int rowid = blockIdx.x;                  // (g*10+r)*1000 + s
  int gr = rowid / 1000, s = rowid % 1000;
  float ds = dis[rowid];
  const float* ap = A + (size_t)rowid * 1000;
  u16* anp = An + (size_t)rowid * SP;
  int t4 = threadIdx.x * 4;                // 0..1020
  if (t4 < 1000) {
    float4 a4 = *(const float4*)(ap + t4);
    float4 d4 = *(const float4*)(dis + gr * 1000 + t4);
    float v0 = ds * d4.x * (a4.x + ((t4 + 0) == s ? 1.f : 0.f));
    float v1 = ds * d4.y * (a4.y + ((t4 + 1) == s ? 1.f : 0.f));
    float v2 = ds * d4.z * (a4.z + ((t4 + 2) == s ? 1.f : 0.f));
    float v3 = ds * d4.w * (a4.w + ((t4 + 3) == s ? 1.f : 0.f));
    usvec4 o = {f2bf(v0), f2bf(v1), f2bf(v2), f2bf(v3)};
    *(usvec4*)(anp + t4) = o;
  } else {
    usvec4 o = {0, 0, 0, 0};
    *(usvec4*)(anp + t4) = o;
  }
}

// ---------------- K3: inp prep, transposed d-major: inpT[b][d 0..95][n] ----------------
__global__ __launch_bounds__(256) void prep_inpT_kernel(const float* __restrict__ x_t,
                                                        const float* __restrict__ h_prev,
                                                        u16* __restrict__ inpT)
{
  int b = blockIdx.y, n0 = blockIdx.x * 64;
  __shared__ float t[64][97];
  for (int idx = threadIdx.x; idx < 2048; idx += 256) {
    int ni = idx >> 5, d = idx & 31;
    int n = n0 + ni;
    t[ni][d] = (n < Nn) ? x_t[(size_t)(b * Nn + n) * 32 + d] : 0.f;
  }
  for (int idx = threadIdx.x; idx < 4096; idx += 256) {
    int ni = idx >> 6, d = idx & 63;
    int n = n0 + ni;
    t[ni][32 + d] = (n < Nn) ? h_prev[(size_t)(b * Nn + n) * 64 + d] : 0.f;
  }
  __syncthreads();
  for (int idx = threadIdx.x; idx < 6144; idx += 256) {
    int d = idx >> 6, ni = idx & 63;
    inpT[(size_t)b * (96 * NPAD) + (size_t)d * NPAD + n0 + ni] = f2bf(t[ni][d]);
  }
}

// ---------------- K4: fused GEMM  outs_p = relu( (An @ inp) @ W_p ) ----------------
// grid (8 mtiles, 16 b, 40 gr), block 256 (4 waves, wave = 32 rows x 96 cols)
template <int NPROJ>
__global__ __launch_bounds__(256) void gemm_pass_kernel(
    const u16* __restrict__ An,     // [40][1000][1024] bf16
    const u16* __restrict__ inpT,   // [16][96][10048]  bf16
    const u16* __restrict__ Wt,     // [NPROJ][4][64][96] bf16 (W^T per g)
    u16* __restrict__ outs0, u16* __restrict__ outs1)
{
  constexpr int BT_OFF = 128 * 40;  // 5120 ushorts
  __shared__ __align__(16) u16 lds_main[12288];          // 24 KB -> 6 blocks/CU

  const int tid = threadIdx.x;
  const int lane = tid & 63, wid = tid >> 6;
  const int mt = blockIdx.x, b = blockIdx.y, gr = blockIdx.z;
  const int g = gr / Rr, r = gr % Rr;
  const int m0 = mt * 128;
  const int wrow0 = wid * 32;
  const int lr = lane & 15, lk = (lane >> 4) << 3;

  const u16* Ap = An + (size_t)gr * (Ss * SP);
  const u16* Bp = inpT + (size_t)b * (96 * NPAD) + r * Ss;

  fvec4 acc[2][6];
  #pragma unroll
  for (int i = 0; i < 2; ++i)
    #pragma unroll
    for (int j = 0; j < 6; ++j) acc[i][j] = (fvec4){0.f, 0.f, 0.f, 0.f};

  #pragma unroll 1
  for (int kk = 0; kk < SP; kk += 32) {
    __syncthreads();
    #pragma unroll
    for (int s2 = 0; s2 < 2; ++s2) {
      int seg = tid + (s2 << 8);
      int row = seg >> 2, kl = (seg & 3) << 3;
      int srow = m0 + row;
      bfrag8 v = (bfrag8){0, 0, 0, 0, 0, 0, 0, 0};
      if (srow < Ss) v = *(const bfrag8*)(Ap + (size_t)srow * SP + kk + kl);
      *(bfrag8*)&lds_main[row * 40 + kl] = v;
    }
    {
      int d = tid >> 2, tl = (tid & 3) << 3;
      *(bfrag8*)&lds_main[BT_OFF + d * 40 + tl] = *(const bfrag8*)(Bp + (size_t)d * NPAD + kk + tl);
      if (tid < 128) {
        int seg = 256 + tid;
        int d2 = seg >> 2, t2 = (seg & 3) << 3;
        *(bfrag8*)&lds_main[BT_OFF + d2 * 40 + t2] = *(const bfrag8*)(Bp + (size_t)d2 * NPAD + kk + t2);
      }
    }
    __syncthreads();
    bfrag8 af0 = *(const bfrag8*)&lds_main[(wrow0 + lr) * 40 + lk];
    bfrag8 af1 = *(const bfrag8*)&lds_main[(wrow0 + 16 + lr) * 40 + lk];
    #pragma unroll
    for (int nf = 0; nf < 6; ++nf) {
      bfrag8 bfr = *(const bfrag8*)&lds_main[BT_OFF + (nf * 16 + lr) * 40 + lk];
      acc[0][nf] = __builtin_amdgcn_mfma_f32_16x16x32_bf16(af0, bfr, acc[0][nf], 0, 0, 0);
      acc[1][nf] = __builtin_amdgcn_mfma_f32_16x16x32_bf16(af1, bfr, acc[1][nf], 0, 0, 0);
    }
  }

  // epilogue stage 1: Ai (f32 acc) -> LDS bf16 [128][96]
  __syncthreads();
  #pragma unroll
  for (int mf = 0; mf < 2; ++mf)
    #pragma unroll
    for (int nf = 0; nf < 6; ++nf)
      #pragma unroll
      for (int j = 0; j < 4; ++j) {
        int row = wrow0 + mf * 16 + ((lane >> 4) << 2) + j;
        lds_main[row * 96 + nf * 16 + lr] = f2bf(acc[mf][nf][j]);
      }
  __syncthreads();

  // epilogue stage 2: per proj, [32x96] @ [96x64] + relu + store (W from L2)
  const int obase = ((g * Bc + b) * Nn + r * Ss) * 64;
  #pragma unroll
  for (int p = 0; p < NPROJ; ++p) {
    const u16* Wg = Wt + (size_t)(p * Gg + g) * 6144;    // [64 e][96 d]
    fvec4 acc2[2][4];
    #pragma unroll
    for (int i = 0; i < 2; ++i)
      #pragma unroll
      for (int j = 0; j < 4; ++j) acc2[i][j] = (fvec4){0.f, 0.f, 0.f, 0.f};
    #pragma unroll
    for (int dk = 0; dk < 96; dk += 32) {
      bfrag8 x0 = *(const bfrag8*)&lds_main[(wrow0 + lr) * 96 + dk + lk];
      bfrag8 x1 = *(const bfrag8*)&lds_main[(wrow0 + 16 + lr) * 96 + dk + lk];
      #pragma unroll
      for (int ef = 0; ef < 4; ++ef) {
        bfrag8 wv = *(const bfrag8*)&Wg[(ef * 16 + lr) * 96 + dk + lk];
        acc2[0][ef] = __builtin_amdgcn_mfma_f32_16x16x32_bf16(x0, wv, acc2[0][ef], 0, 0, 0);
        acc2[1][ef] = __builtin_amdgcn_mfma_f32_16x16x32_bf16(x1, wv, acc2[1][ef], 0, 0, 0);
      }
    }
    u16* op = (p == 0) ? outs0 : outs1;
    #pragma unroll
    for (int mf = 0; mf < 2; ++mf)
      #pragma unroll
      for (int ef = 0; ef < 4; ++ef)
        #pragma unroll
        for (int j = 0; j < 4; ++j) {
          int srow = m0 + wrow0 + mf * 16 + ((lane >> 4) << 2) + j;
          if (srow < Ss) {
            float v = fmaxf(acc2[mf][ef][j], 0.f);
            op[obase + srow * 64 + ef * 16 + lr] = f2bf(v);
          }
        }
  }
}

// ---------------- K5 v2: MFMA attention combine (MODE 0=U sigmoid, 1=R cand, 2=C final) ----------------
// grid 500 blocks x 256 thr; each block: 5 tiles of 64 rows. z-GEMM [64x256]@[256x64] via MFMA.
template <int MODE>
__global__ __launch_bounds__(256) void attn_kernel(
    const u16* __restrict__ outs,      // [4][160000][64] bf16 (relu'd)
    const float* __restrict__ rs,      // [160000][2]
    const u16* __restrict__ a1wb,      // [258][64] bf16
    const float* __restrict__ a1b, const float* __restrict__ a2w, const float* __restrict__ a2b,
    const float* __restrict__ h_prev, const float* __restrict__ u_sig_in,
    float* __restrict__ usig_out, u16* __restrict__ candh_out, float* __restrict__ out_final)
{
  __shared__ __align__(16) u16 a1wT[16384];    // [64 e][256 k], XOR-swizzled
  __shared__ __align__(16) u16 Hs[16384];      // [64 row][256 k], XOR-swizzled
  __shared__ __align__(16) float alpha_s[256]; // [64 row][4 g]

  const int tid = threadIdx.x, lane = tid & 63, w = tid >> 6;
  const int lr16 = lane & 15, hi4 = lane >> 4;
  const int lk = hi4 << 3;
  const int w16 = w * 16;

  // stage a1w transposed: a1wT[e][k] = a1wb[k][e], k<256 (swizzled)
  {
    int e = tid & 63, kb = (tid >> 6) * 64;
    for (int i = 0; i < 64; ++i) {
      int k = kb + i;
      a1wT[(e * 256 + k) ^ ((e & 7) << 3)] = a1wb[k * 64 + e];
    }
  }

  // hoisted per-lane constants (cols e' = ef*16+lr16)
  float a1b_v[4], w256v[4], w257v[4], a2w_l[16], a2b_v[4];
  #pragma unroll
  for (int ef = 0; ef < 4; ++ef) {
    int e = ef * 16 + lr16;
    a1b_v[ef] = a1b[e];
    w256v[ef] = bf2f(a1wb[256 * 64 + e]);
    w257v[ef] = bf2f(a1wb[257 * 64 + e]);
    #pragma unroll
    for (int g = 0; g < 4; ++g) a2w_l[ef * 4 + g] = a2w[e * 4 + g];
  }
  #pragma unroll
  for (int g = 0; g < 4; ++g) a2b_v[g] = a2b[g];

  for (int it = 0; it < 5; ++it) {
    const int row0 = (blockIdx.x * 5 + it) * 64;
    __syncthreads();                      // previous tile's Hs reads done
    // stage H: Hs[ri][g*64+e] = outs[g][row0+ri][e] (swizzled, b128)
    #pragma unroll
    for (int j = 0; j < 8; ++j) {
      int c = tid + j * 256;              // 2048 chunks of 8 u16
      int g = c >> 9, rem = c & 511, ri = rem >> 3, e8 = rem & 7;
      bfrag8 v = *(const bfrag8*)&outs[((size_t)g * (Bc * Nn) + row0 + ri) * 64 + e8 * 8];
      *(bfrag8*)&Hs[(ri * 256 + g * 64 + e8 * 8) ^ ((ri & 7) << 3)] = v;
    }
    __syncthreads();

    // z-GEMM: wave w -> rows w16..w16+15, all 64 e-cols
    fvec4 zacc[4];
    #pragma unroll
    for (int ef = 0; ef < 4; ++ef) zacc[ef] = (fvec4){0.f, 0.f, 0.f, 0.f};
    #pragma unroll
    for (int ks = 0; ks < 8; ++ks) {
      bfrag8 af = *(const bfrag8*)&Hs[((w16 + lr16) * 256 + ks * 32 + lk) ^ ((lr16 & 7) << 3)];
      #pragma unroll
      for (int ef = 0; ef < 4; ++ef) {
        bfrag8 bf = *(const bfrag8*)&a1wT[((ef * 16 + lr16) * 256 + ks * 32 + lk) ^ ((lr16 & 7) << 3)];
        zacc[ef] = __builtin_amdgcn_mfma_f32_16x16x32_bf16(af, bf, zacc[ef], 0, 0, 0);
      }
    }

    // rs rows + relu + a2w partial products; rows handled: w16 + hi4*4 + j
    float r0[4], r1[4];
    #pragma unroll
    for (int j = 0; j < 4; ++j) {
      int rrow = row0 + w16 + hi4 * 4 + j;
      float2 rv = *(const float2*)(rs + (size_t)rrow * 2);
      r0[j] = rv.x; r1[j] = rv.y;
    }
    float pj[16];                          // [j][g]
    #pragma unroll
    for (int i = 0; i < 16; ++i) pj[i] = 0.f;
    #pragma unroll
    for (int ef = 0; ef < 4; ++ef)
      #pragma unroll
      for (int j = 0; j < 4; ++j) {
        float zv = zacc[ef][j] + a1b_v[ef] + r0[j] * w256v[ef] + r1[j] * w257v[ef];
        zv = fmaxf(zv, 0.f);
        #pragma unroll
        for (int g = 0; g < 4; ++g) pj[j * 4 + g] = fmaf(zv, a2w_l[ef * 4 + g], pj[j * 4 + g]);
      }
    #pragma unroll
    for (int off = 1; off <= 8; off <<= 1)
      #pragma unroll
      for (int i = 0; i < 16; ++i) pj[i] += __shfl_xor(pj[i], off);

    // softmax + bias; lanes lr16<4 write alpha
    #pragma unroll
    for (int j = 0; j < 4; ++j) {
      float p0 = pj[j * 4 + 0] + a2b_v[0], p1 = pj[j * 4 + 1] + a2b_v[1];
      float p2 = pj[j * 4 + 2] + a2b_v[2], p3 = pj[j * 4 + 3] + a2b_v[3];
      float m = fmaxf(fmaxf(p0, p1), fmaxf(p2, p3));
      float e0 = __expf(p0 - m), e1 = __expf(p1 - m), e2 = __expf(p2 - m), e3 = __expf(p3 - m);
      if (r1[j] > 0.5f) { e0 *= 1.1f; e1 *= 1.1f; e2 *= 1.1f; e3 *= 2.0f; }
      float inv = 1.f / (e0 + e1 + e2 + e3);
      if (lr16 < 4) {
        float esel = (lr16 == 0) ? e0 : (lr16 == 1) ? e1 : (lr16 == 2) ? e2 : e3;
        alpha_s[(w16 + hi4 * 4 + j) * 4 + lr16] = esel * inv;
      }
    }

    // comb + epilogue: lane = e, rows w16..w16+15 (same wave -> no barrier needed)
    #pragma unroll 1
    for (int rr = 0; rr < 16; ++rr) {
      int lrow = w16 + rr;
      float4 av = *(const float4*)&alpha_s[lrow * 4];
      int sw = (lrow & 7) << 3, base = lrow * 256;
      float cmb = av.x * bf2f(Hs[(base + lane) ^ sw])
                + av.y * bf2f(Hs[(base + 64 + lane) ^ sw])
                + av.z * bf2f(Hs[(base + 128 + lane) ^ sw])
                + av.w * bf2f(Hs[(base + 192 + lane) ^ sw]);
      size_t gi = (size_t)(row0 + lrow) * 64 + lane;
      if (MODE == 0) {
        usig_out[gi] = 1.f / (1.f + __expf(-cmb));
      } else if (MODE == 1) {
        candh_out[gi] = f2bf(cmb * h_prev[gi]);
      } else {
        float u = u_sig_in[gi], hp = h_prev[gi];
        out_final[gi] = u * tanhf(cmb) + (1.f - u) * hp;
      }
    }
  }
}

// ---------------- K6: transpose candh [b][n][e] -> inpT rows d=32..95 ----------------
__global__ __launch_bounds__(256) void transpose_cand_kernel(const u16* __restrict__ candh,
                                                             u16* __restrict__ inpT)
{
  int b = blockIdx.y, n0 = blockIdx.x * 64;
  __shared__ float t[64][65];
  for (int idx = threadIdx.x; idx < 4096; idx += 256) {
    int ni = idx >> 6, e = idx & 63;
    int n = n0 + ni;
    t[ni][e] = (n < Nn) ? bf2f(candh[(size_t)(b * Nn + n) * 64 + e]) : 0.f;
  }
  __syncthreads();
  for (int idx = threadIdx.x; idx < 4096; idx += 256) {
    int e = idx >> 6, ni = idx & 63;
    inpT[(size_t)b * (96 * NPAD) + (size_t)(32 + e) * NPAD + n0 + ni] = f2bf(t[ni][e]);
  }
}

// ---------------- host ----------------
extern "C" void kernel_launch(void* const* d_in, const int* in_sizes, int n_in,
                              void* d_out, int out_size, void* d_ws, size_t ws_size,
                              hipStream_t stream) {
  (void)in_sizes; (void)n_in; (void)out_size; (void)ws_size;
  const float* x_t    = (const float*)d_in[0];
  const float* h_prev = (const float*)d_in[1];
  const float* A      = (const float*)d_in[2];
  const float* rs     = (const float*)d_in[3];
  const float* W_u    = (const float*)d_in[4];
  const float* a1w_u  = (const float*)d_in[5];
  const float* a1b_u  = (const float*)d_in[6];
  const float* a2w_u  = (const float*)d_in[7];
  const float* a2b_u  = (const float*)d_in[8];
  const float* W_r    = (const float*)d_in[9];
  const float* a1w_r  = (const float*)d_in[10];
  const float* a1b_r  = (const float*)d_in[11];
  const float* a2w_r  = (const float*)d_in[12];
  const float* a2b_r  = (const float*)d_in[13];
  const float* W_c    = (const float*)d_in[14];
  const float* a1w_c  = (const float*)d_in[15];
  const float* a1b_c  = (const float*)d_in[16];
  const float* a2w_c  = (const float*)d_in[17];
  const float* a2b_c  = (const float*)d_in[18];
  float* out = (float*)d_out;

  char* ws = (char*)d_ws;
  const size_t AN_OFF    = 0;                                  // 81,920,000 B
  const size_t DIS_OFF   = 81920000;                           // 160,000 B
  const size_t INPT_OFF  = 82080000;                           // 30,867,456 B
  const size_t OUTSU_OFF = 112947456;                          // 81,920,000 B
  const size_t OUTSR_OFF = 194867456;                          // 81,920,000 B
  const size_t USIG_OFF  = 276787456;                          // 40,960,000 B
  const size_t CANDH_OFF = 317747456;                          // 20,480,000 B
  const size_t WT_OFF    = 338227456;
  const size_t A1WB_OFF  = 338374912;

  u16* An    = (u16*)(ws + AN_OFF);
  float* dis = (float*)(ws + DIS_OFF);
  u16* inpT  = (u16*)(ws + INPT_OFF);
  u16* outsU = (u16*)(ws + OUTSU_OFF);
  u16* outsR = (u16*)(ws + OUTSR_OFF);
  u16* outsC = outsU;                                          // reuse after attn_U
  float* usig = (float*)(ws + USIG_OFF);
  u16* candh = (u16*)(ws + CANDH_OFF);
  u16* Wt    = (u16*)(ws + WT_OFF);
  u16* a1wb  = (u16*)(ws + A1WB_OFF);

  prep_weights_kernel<<<482, 256, 0, stream>>>(W_u, W_r, W_c, a1w_u, a1w_r, a1w_c, Wt, a1wb);
  rowsum_kernel<<<10000, 256, 0, stream>>>(A, dis);
  build_an_kernel<<<40000, 256, 0, stream>>>(A, dis, An);
  prep_inpT_kernel<<<dim3(157, 16), 256, 0, stream>>>(x_t, h_prev, inpT);

  gemm_pass_kernel<2><<<dim3(8, 16, 40), 256, 0, stream>>>(An, inpT, Wt, outsU, outsR);

  attn_kernel<0><<<500, 256, 0, stream>>>(outsU, rs, a1wb, a1b_u, a2w_u, a2b_u,
                                          nullptr, nullptr, usig, nullptr, nullptr);
  attn_kernel<1><<<500, 256, 0, stream>>>(outsR, rs, a1wb + 16512, a1b_r, a2w_r, a2b_r,
                                          h_prev, nullptr, nullptr, candh, nullptr);
  transpose_cand_kernel<<<dim3(157, 16), 256, 0, stream>>>(candh, inpT);

  gemm_pass_kernel<1><<<dim3(8, 16, 40), 256, 0, stream>>>(An, inpT, Wt + 2 * 24576, outsC, nullptr);

  attn_kernel<2><<<500, 256, 0, stream>>>(outsC, rs, a1wb + 2 * 16512, a1b_c, a2w_c, a2b_c,
                                          h_prev, usig, nullptr, nullptr, out);
}

// Round 3
// 956.695 us; speedup vs baseline: 1.9753x; 1.2085x over previous
//
#include <hip/hip_runtime.h>

typedef unsigned short u16;
typedef __attribute__((ext_vector_type(8))) short bfrag8;     // 8 bf16 = 4 VGPR (MFMA A/B frag)
typedef __attribute__((ext_vector_type(4))) float fvec4;      // MFMA C/D frag
typedef __attribute__((ext_vector_type(4))) unsigned short usvec4;

// ---- problem constants ----
#define Bc   16
#define Nn   10000
#define Rr   10
#define Ss   1000
#define Gg   4
#define SP   1024      // K-padded S
#define MP   1024      // M-padded S (An rows padded with zeros)
#define NPAD 10048     // padded node count for inpT / hwcT

__device__ __forceinline__ float bf2f(u16 u) {
  union { unsigned int i; float f; } x; x.i = ((unsigned int)u) << 16; return x.f;
}
__device__ __forceinline__ u16 f2bf(float f) {
  unsigned int x = __float_as_uint(f);
  unsigned int r = x + 0x7FFFu + ((x >> 16) & 1u);   // RNE; no NaNs in this workload
  return (u16)(r >> 16);
}

// async global->LDS, 16B per lane; dest = wave-uniform base + lane*16
__device__ __forceinline__ void glds16(const u16* gsrc, u16* ldst) {
  __builtin_amdgcn_global_load_lds((const __attribute__((address_space(1))) unsigned int*)gsrc,
                                   (__attribute__((address_space(3))) unsigned int*)ldst, 16, 0, 0);
}

// stage a [nloads*8 rows][64 k] bf16 tile: linear LDS dest, source pre-swizzled so that
// reads with byte ^= ((row&7)<<4) are conflict-free.
__device__ __forceinline__ void stage_tile(const u16* gsrc, size_t rstride, int nloads,
                                           u16* ldsbase, int wid, int lane) {
  int rsub = lane >> 3;
  int kb8 = ((lane & 7) ^ rsub) << 3;          // swizzled k-offset in u16 (chunk*8)
  for (int i = wid; i < nloads; i += 4)
    glds16(gsrc + (size_t)(8 * i + rsub) * rstride + kb8, ldsbase + i * 512);
}

// swizzled fragment read from a [rows][64 k] tile (kbyte = ks*64 + hi*16)
__device__ __forceinline__ bfrag8 ldsw(const u16* base, int row, int kbyte) {
  int off = row * 128 + (kbyte ^ ((row & 7) << 4));
  return *(const bfrag8*)((const char*)base + off);
}

// ---------------- K0: weight prep ----------------
__global__ __launch_bounds__(256) void prep_weights_kernel(
    const float* __restrict__ Wu, const float* __restrict__ Wr, const float* __restrict__ Wc,
    const float* __restrict__ a1u, const float* __restrict__ a1r, const float* __restrict__ a1c,
    u16* __restrict__ Wt, u16* __restrict__ a1wb, u16* __restrict__ a1wT)
{
  int idx = blockIdx.x * 256 + threadIdx.x;
  if (idx < 73728) {                       // Wt[p][g][e][d] = W[g][d][e]
    int p = idx / 24576, rem = idx % 24576;
    int g = rem / 6144, r2 = rem % 6144;
    int e = r2 / 96, dd = r2 % 96;
    const float* W = (p == 0) ? Wu : (p == 1) ? Wr : Wc;
    Wt[idx] = f2bf(W[(g * 96 + dd) * 64 + e]);
  } else if (idx < 73728 + 49536) {        // a1wb[p][k][e] (k<258)
    int j = idx - 73728;
    int p = j / 16512, k = j % 16512;
    const float* s = (p == 0) ? a1u : (p == 1) ? a1r : a1c;
    a1wb[j] = f2bf(s[k]);
  } else if (idx < 73728 + 49536 + 49152) {// a1wT[p][e][k] = a1w[k][e], k<256
    int j = idx - 123264;
    int p = j / 16384, rem = j % 16384;
    int e = rem / 256, k = rem % 256;
    const float* s = (p == 0) ? a1u : (p == 1) ? a1r : a1c;
    a1wT[j] = f2bf(s[k * 64 + e]);
  }
}

// ---------------- K1: row sums -> deg^-0.5 ----------------
__global__ __launch_bounds__(256) void rowsum_kernel(const float* __restrict__ A,
                                                     float* __restrict__ dis)
{
  int wid = threadIdx.x >> 6, lane = threadIdx.x & 63;
  int row = blockIdx.x * 4 + wid;          // 40000 rows
  const float* ap = A + (size_t)row * 1000;
  float s = 0.f;
  for (int i = lane; i < 250; i += 64) {
    float4 v = *(const float4*)(ap + i * 4);
    s += (v.x + v.y) + (v.z + v.w);
  }
  #pragma unroll
  for (int off = 32; off >= 1; off >>= 1) s += __shfl_xor(s, off);
  if (lane == 0) dis[row] = rsqrtf(fmaxf(s, 1e-5f));
}

// ---------------- K2: build An (bf16, K padded to 1024, M padded to 1024 with zero rows) ----
__global__ __launch_bounds__(256) void build_an_kernel(const float* __restrict__ A,
                                                       const float* __restrict__ dis,
                                                       u16* __restrict__ An)
{
  int gr = blockIdx.x >> 10, s = blockIdx.x & 1023;
  u16* anp = An + (size_t)blockIdx.x * 1024;      // (gr*1024+s)*1024
  int t4 = threadIdx.x * 4;
  if (s >= Ss || t4 >= 1000) {
    usvec4 z = {0, 0, 0, 0};
    *(usvec4*)(anp + t4) = z;
    return;
  }
  int rowid = gr * 1000 + s;
  float ds = dis[rowid];
  const float* ap = A + (size_t)rowid * 1000;
  float4 a4 = *(const float4*)(ap + t4);
  float4 d4 = *(const float4*)(dis + gr * 1000 + t4);
  float v0 = ds * d4.x * (a4.x + ((t4 + 0) == s ? 1.f : 0.f));
  float v1 = ds * d4.y * (a4.y + ((t4 + 1) == s ? 1.f : 0.f));
  float v2 = ds * d4.z * (a4.z + ((t4 + 2) == s ? 1.f : 0.f));
  float v3 = ds * d4.w * (a4.w + ((t4 + 3) == s ? 1.f : 0.f));
  usvec4 o = {f2bf(v0), f2bf(v1), f2bf(v2), f2bf(v3)};
  *(usvec4*)(anp + t4) = o;
}

// ---------------- K3: inp prep -> inpT[b][d][n] (d-major) + candb x-part [t][0..31] ------
__global__ __launch_bounds__(256) void prep_inpT_kernel(const float* __restrict__ x_t,
                                                        const float* __restrict__ h_prev,
                                                        u16* __restrict__ inpT,
                                                        u16* __restrict__ candb)
{
  int b = blockIdx.y, n0 = blockIdx.x * 64;
  __shared__ float t[64][97];
  for (int idx = threadIdx.x; idx < 2048; idx += 256) {
    int ni = idx >> 5, d = idx & 31;
    int n = n0 + ni;
    t[ni][d] = (n < Nn) ? x_t[(size_t)(b * Nn + n) * 32 + d] : 0.f;
  }
  for (int idx = threadIdx.x; idx < 4096; idx += 256) {
    int ni = idx >> 6, d = idx & 63;
    int n = n0 + ni;
    t[ni][32 + d] = (n < Nn) ? h_prev[(size_t)(b * Nn + n) * 64 + d] : 0.f;
  }
  __syncthreads();
  for (int idx = threadIdx.x; idx < 6144; idx += 256) {
    int d = idx >> 6, ni = idx & 63;
    inpT[(size_t)b * (96 * NPAD) + (size_t)d * NPAD + n0 + ni] = f2bf(t[ni][d]);
  }
  for (int idx = threadIdx.x; idx < 2048; idx += 256) {
    int ni = idx >> 5, d = idx & 31;
    int n = n0 + ni;
    if (n < Nn) candb[((size_t)b * Nn + n) * 96 + d] = f2bf(t[ni][d]);
  }
}

// ---------------- K4: GEMM1  Ai = An @ inp, then project to U,R (fused epilogue) ---------
// grid (8 mt, 16 b, 40 gr), 256 thr (4 waves 2x2), tile 128x96, BK=64
__global__ __launch_bounds__(256) void gemm_uv_kernel(
    const u16* __restrict__ An,     // [40][1024][1024]
    const u16* __restrict__ inpT,   // [16][96][NPAD]
    const u16* __restrict__ Wt,     // [3][4][64][96]
    u16* __restrict__ outs0, u16* __restrict__ outs1)
{
  __shared__ __align__(1024) u16 lds[14336];   // A tile 8192, B tile 6144 @8192; epi [128][104]

  const int tid = threadIdx.x, lane = tid & 63, wid = tid >> 6;
  const int mt = blockIdx.x, b = blockIdx.y, gr = blockIdx.z;
  const int g = gr / Rr, r = gr % Rr;
  const int m0 = mt * 128;
  const int wrow0 = (wid >> 1) * 64, wcol0 = (wid & 1) * 48;
  const int lr = lane & 15, hi = lane >> 4;
  const int kbhi = hi * 16;

  const u16* Ap = An + (size_t)gr * (MP * SP) + (size_t)m0 * SP;
  const u16* Bp = inpT + (size_t)b * (96 * NPAD) + r * Ss;

  fvec4 acc[4][3];
  #pragma unroll
  for (int i = 0; i < 4; ++i)
    #pragma unroll
    for (int j = 0; j < 3; ++j) acc[i][j] = (fvec4){0.f, 0.f, 0.f, 0.f};

  #pragma unroll 1
  for (int kt = 0; kt < 16; ++kt) {
    const int kk = kt * 64;
    __syncthreads();
    stage_tile(Ap + kk, SP, 16, lds, wid, lane);
    stage_tile(Bp + kk, NPAD, 12, lds + 8192, wid, lane);
    __syncthreads();
    #pragma unroll
    for (int ks = 0; ks < 2; ++ks) {
      bfrag8 a[4], bb[3];
      #pragma unroll
      for (int mfi = 0; mfi < 4; ++mfi) a[mfi] = ldsw(lds, wrow0 + mfi * 16 + lr, ks * 64 + kbhi);
      #pragma unroll
      for (int nfi = 0; nfi < 3; ++nfi) bb[nfi] = ldsw(lds + 8192, wcol0 + nfi * 16 + lr, ks * 64 + kbhi);
      #pragma unroll
      for (int mfi = 0; mfi < 4; ++mfi)
        #pragma unroll
        for (int nfi = 0; nfi < 3; ++nfi)
          acc[mfi][nfi] = __builtin_amdgcn_mfma_f32_16x16x32_bf16(a[mfi], bb[nfi], acc[mfi][nfi], 0, 0, 0);
    }
  }

  // epilogue stage 1: Ai -> LDS bf16 [128][104] (padded stride)
  __syncthreads();
  #pragma unroll
  for (int mfi = 0; mfi < 4; ++mfi)
    #pragma unroll
    for (int nfi = 0; nfi < 3; ++nfi)
      #pragma unroll
      for (int j = 0; j < 4; ++j) {
        int row = wrow0 + mfi * 16 + hi * 4 + j;
        int col = wcol0 + nfi * 16 + lr;
        lds[row * 104 + col] = f2bf(acc[mfi][nfi][j]);
      }
  __syncthreads();

  // epilogue stage 2: [32x96] @ [96x64] per proj + relu + store (W from L2)
  const int s2r0 = wid * 32;
  const int obase = ((g * Bc + b) * Nn + r * Ss) * 64;
  #pragma unroll
  for (int p = 0; p < 2; ++p) {
    const u16* Wg = Wt + (size_t)(p * Gg + g) * 6144;    // [64 e][96 d]
    fvec4 acc2[2][4];
    #pragma unroll
    for (int i = 0; i < 2; ++i)
      #pragma unroll
      for (int j = 0; j < 4; ++j) acc2[i][j] = (fvec4){0.f, 0.f, 0.f, 0.f};
    #pragma unroll
    for (int dk = 0; dk < 3; ++dk) {
      bfrag8 x0 = *(const bfrag8*)&lds[(s2r0 + lr) * 104 + dk * 32 + kbhi / 2];
      bfrag8 x1 = *(const bfrag8*)&lds[(s2r0 + 16 + lr) * 104 + dk * 32 + kbhi / 2];
      #pragma unroll
      for (int ef = 0; ef < 4; ++ef) {
        bfrag8 wv = *(const bfrag8*)&Wg[(ef * 16 + lr) * 96 + dk * 32 + kbhi / 2];
        acc2[0][ef] = __builtin_amdgcn_mfma_f32_16x16x32_bf16(x0, wv, acc2[0][ef], 0, 0, 0);
        acc2[1][ef] = __builtin_amdgcn_mfma_f32_16x16x32_bf16(x1, wv, acc2[1][ef], 0, 0, 0);
      }
    }
    u16* op = (p == 0) ? outs0 : outs1;
    #pragma unroll
    for (int mf = 0; mf < 2; ++mf)
      #pragma unroll
      for (int ef = 0; ef < 4; ++ef)
        #pragma unroll
        for (int j = 0; j < 4; ++j) {
          int srow = m0 + s2r0 + mf * 16 + hi * 4 + j;
          if (srow < Ss) {
            float v = fmaxf(acc2[mf][ef][j], 0.f);
            op[obase + srow * 64 + ef * 16 + lr] = f2bf(v);
          }
        }
  }
}

// ---------------- K7: cand projection  hwcT[g][b][e][n] = (cand @ W_c)^T ----------------
// grid (157, 16), 256 thr, 4 waves = 4 g; per block: 64 n-rows
__global__ __launch_bounds__(256) void cand_proj_kernel(const u16* __restrict__ candb,
                                                        const u16* __restrict__ Wt,
                                                        u16* __restrict__ hwcT)
{
  __shared__ __align__(16) u16 lds[16384];     // 4 waves x [64 e][64 t]
  const int tid = threadIdx.x, lane = tid & 63, g = tid >> 6;
  const int lr = lane & 15, hi = lane >> 4;
  const int b = blockIdx.y, n0 = blockIdx.x * 64;
  const u16* WcT = Wt + (size_t)(2 * Gg + g) * 6144;   // [64 e][96 d]

  fvec4 acc[4][4];
  #pragma unroll
  for (int i = 0; i < 4; ++i)
    #pragma unroll
    for (int j = 0; j < 4; ++j) acc[i][j] = (fvec4){0.f, 0.f, 0.f, 0.f};

  #pragma unroll
  for (int ks = 0; ks < 3; ++ks) {
    bfrag8 a[4], w[4];
    #pragma unroll
    for (int mfi = 0; mfi < 4; ++mfi)
      a[mfi] = *(const bfrag8*)&candb[((size_t)b * Nn + n0 + mfi * 16 + lr) * 96 + ks * 32 + hi * 8];
    #pragma unroll
    for (int nfi = 0; nfi < 4; ++nfi)
      w[nfi] = *(const bfrag8*)&WcT[(nfi * 16 + lr) * 96 + ks * 32 + hi * 8];
    #pragma unroll
    for (int mfi = 0; mfi < 4; ++mfi)
      #pragma unroll
      for (int nfi = 0; nfi < 4; ++nfi)
        acc[mfi][nfi] = __builtin_amdgcn_mfma_f32_16x16x32_bf16(a[mfi], w[nfi], acc[mfi][nfi], 0, 0, 0);
  }

  // bounce to LDS [e][t] per wave, then coalesced transposed store
  #pragma unroll
  for (int mfi = 0; mfi < 4; ++mfi)
    #pragma unroll
    for (int nfi = 0; nfi < 4; ++nfi)
      #pragma unroll
      for (int j = 0; j < 4; ++j) {
        int e = nfi * 16 + lr, tl = mfi * 16 + hi * 4 + j;
        lds[g * 4096 + e * 64 + tl] = f2bf(acc[mfi][nfi][j]);
      }
  __syncthreads();
  #pragma unroll
  for (int i = 0; i < 8; ++i) {
    int e = i * 8 + (lane >> 3), tc = lane & 7;
    bfrag8 v = *(const bfrag8*)&lds[g * 4096 + e * 64 + tc * 8];
    *(bfrag8*)&hwcT[((size_t)g * 1024 + b * 64 + e) * NPAD + n0 + tc * 8] = v;
  }
}

// ---------------- K8: GEMM2  outs_c = relu( An @ hwc ) ----------------
// grid (8 mt, 8 bpair, 40 gr), 256 thr (4 waves 2x2), tile 128x128, BK=64
__global__ __launch_bounds__(256) void gemm_c_kernel(
    const u16* __restrict__ An,     // [40][1024][1024]
    const u16* __restrict__ hwcT,   // [4][1024 rows=(b,e)][NPAD]
    u16* __restrict__ outs0)
{
  __shared__ __align__(1024) u16 lds[16384];   // A 8192 + B 8192

  const int tid = threadIdx.x, lane = tid & 63, wid = tid >> 6;
  const int mt = blockIdx.x, by = blockIdx.y, gr = blockIdx.z;
  const int g = gr / Rr, r = gr % Rr;
  const int m0 = mt * 128;
  const int wrow0 = (wid >> 1) * 64, wcol0 = (wid & 1) * 64;
  const int lr = lane & 15, hi = lane >> 4;
  const int kbhi = hi * 16;

  const u16* Ap = An + (size_t)gr * (MP * SP) + (size_t)m0 * SP;
  const u16* Bp = hwcT + (size_t)(g * 1024 + by * 128) * NPAD + r * Ss;

  fvec4 acc[4][4];
  #pragma unroll
  for (int i = 0; i < 4; ++i)
    #pragma unroll
    for (int j = 0; j < 4; ++j) acc[i][j] = (fvec4){0.f, 0.f, 0.f, 0.f};

  #pragma unroll 1
  for (int kt = 0; kt < 16; ++kt) {
    const int kk = kt * 64;
    __syncthreads();
    stage_tile(Ap + kk, SP, 16, lds, wid, lane);
    stage_tile(Bp + kk, NPAD, 16, lds + 8192, wid, lane);
    __syncthreads();
    #pragma unroll
    for (int ks = 0; ks < 2; ++ks) {
      bfrag8 a[4], bb[4];
      #pragma unroll
      for (int mfi = 0; mfi < 4; ++mfi) a[mfi] = ldsw(lds, wrow0 + mfi * 16 + lr, ks * 64 + kbhi);
      #pragma unroll
      for (int nfi = 0; nfi < 4; ++nfi) bb[nfi] = ldsw(lds + 8192, wcol0 + nfi * 16 + lr, ks * 64 + kbhi);
      #pragma unroll
      for (int mfi = 0; mfi < 4; ++mfi)
        #pragma unroll
        for (int nfi = 0; nfi < 4; ++nfi)
          acc[mfi][nfi] = __builtin_amdgcn_mfma_f32_16x16x32_bf16(a[mfi], bb[nfi], acc[mfi][nfi], 0, 0, 0);
    }
  }

  // direct store: relu, col -> (b, e)
  #pragma unroll
  for (int mfi = 0; mfi < 4; ++mfi)
    #pragma unroll
    for (int nfi = 0; nfi < 4; ++nfi)
      #pragma unroll
      for (int j = 0; j < 4; ++j) {
        int srow = m0 + wrow0 + mfi * 16 + hi * 4 + j;
        if (srow < Ss) {
          int col = wcol0 + nfi * 16 + lr;
          int bb2 = by * 2 + (col >> 6), e = col & 63;
          int n = r * Ss + srow;
          outs0[(((size_t)g * Bc + bb2) * Nn + n) * 64 + e] = f2bf(fmaxf(acc[mfi][nfi][j], 0.f));
        }
      }
}

// ---------------- K5: MFMA attention combine (MODE 0=U sigmoid, 1=R cand, 2=C final) -----
// grid 2500, 256 thr; one 64-row tile per block
template <int MODE>
__global__ __launch_bounds__(256) void attn_kernel(
    const u16* __restrict__ outs,      // [4][160000][64] bf16 (relu'd)
    const float* __restrict__ rs,      // [160000][2]
    const u16* __restrict__ a1wT,      // [64 e][256 k] bf16 (pre-transposed)
    const u16* __restrict__ a1wb,      // [258][64] bf16 (rows 256/257 used)
    const float* __restrict__ a1b, const float* __restrict__ a2w, const float* __restrict__ a2b,
    const float* __restrict__ h_prev, const u16* __restrict__ usig_in,
    u16* __restrict__ usig_out, u16* __restrict__ candb_out, float* __restrict__ out_final)
{
  __shared__ __align__(16) u16 Hs[16384];      // [64 row][256 k], XOR-swizzled
  __shared__ __align__(16) float alpha_s[256]; // [64 row][4 g]

  const int tid = threadIdx.x, lane = tid & 63, w = tid >> 6;
  const int lr16 = lane & 15, hi4 = lane >> 4;
  const int lk = hi4 << 3;
  const int w16 = w * 16;
  const int row0 = blockIdx.x * 64;

  // stage H: Hs[ri][g*64+e] = outs[g][row0+ri][e] (swizzled, b128)
  #pragma unroll
  for (int j = 0; j < 8; ++j) {
    int c = tid + j * 256;              // 2048 chunks of 8 u16
    int g = c >> 9, rem = c & 511, ri = rem >> 3, e8 = rem & 7;
    bfrag8 v = *(const bfrag8*)&outs[((size_t)g * (Bc * Nn) + row0 + ri) * 64 + e8 * 8];
    *(bfrag8*)&Hs[(ri * 256 + g * 64 + e8 * 8) ^ ((ri & 7) << 3)] = v;
  }

  // hoisted per-lane constants (cols e' = ef*16+lr16)
  float a1b_v[4], w256v[4], w257v[4], a2w_l[16], a2b_v[4];
  #pragma unroll
  for (int ef = 0; ef < 4; ++ef) {
    int e = ef * 16 + lr16;
    a1b_v[ef] = a1b[e];
    w256v[ef] = bf2f(a1wb[256 * 64 + e]);
    w257v[ef] = bf2f(a1wb[257 * 64 + e]);
    #pragma unroll
    for (int g = 0; g < 4; ++g) a2w_l[ef * 4 + g] = a2w[e * 4 + g];
  }
  #pragma unroll
  for (int g = 0; g < 4; ++g) a2b_v[g] = a2b[g];
  __syncthreads();

  // z-GEMM: wave w -> rows w16..w16+15, all 64 e-cols; B frags from global (L2-hot)
  fvec4 zacc[4];
  #pragma unroll
  for (int ef = 0; ef < 4; ++ef) zacc[ef] = (fvec4){0.f, 0.f, 0.f, 0.f};
  #pragma unroll
  for (int ks = 0; ks < 8; ++ks) {
    bfrag8 af = *(const bfrag8*)&Hs[((w16 + lr16) * 256 + ks * 32 + lk) ^ ((lr16 & 7) << 3)];
    #pragma unroll
    for (int ef = 0; ef < 4; ++ef) {
      bfrag8 bf = *(const bfrag8*)&a1wT[(ef * 16 + lr16) * 256 + ks * 32 + lk];
      zacc[ef] = __builtin_amdgcn_mfma_f32_16x16x32_bf16(af, bf, zacc[ef], 0, 0, 0);
    }
  }

  // rs + relu + a2w partial products; rows handled: w16 + hi4*4 + j
  float r0[4], r1[4];
  #pragma unroll
  for (int j = 0; j < 4; ++j) {
    int rrow = row0 + w16 + hi4 * 4 + j;
    float2 rv = *(const float2*)(rs + (size_t)rrow * 2);
    r0[j] = rv.x; r1[j] = rv.y;
  }
  float pj[16];                          // [j][g]
  #pragma unroll
  for (int i = 0; i < 16; ++i) pj[i] = 0.f;
  #pragma unroll
  for (int ef = 0; ef < 4; ++ef)
    #pragma unroll
    for (int j = 0; j < 4; ++j) {
      float zv = zacc[ef][j] + a1b_v[ef] + r0[j] * w256v[ef] + r1[j] * w257v[ef];
      zv = fmaxf(zv, 0.f);
      #pragma unroll
      for (int g = 0; g < 4; ++g) pj[j * 4 + g] = fmaf(zv, a2w_l[ef * 4 + g], pj[j * 4 + g]);
    }
  #pragma unroll
  for (int off = 1; off <= 8; off <<= 1)
    #pragma unroll
    for (int i = 0; i < 16; ++i) pj[i] += __shfl_xor(pj[i], off);

  // softmax + bias; lanes lr16<4 write alpha
  #pragma unroll
  for (int j = 0; j < 4; ++j) {
    float p0 = pj[j * 4 + 0] + a2b_v[0], p1 = pj[j * 4 + 1] + a2b_v[1];
    float p2 = pj[j * 4 + 2] + a2b_v[2], p3 = pj[j * 4 + 3] + a2b_v[3];
    float m = fmaxf(fmaxf(p0, p1), fmaxf(p2, p3));
    float e0 = __expf(p0 - m), e1 = __expf(p1 - m), e2 = __expf(p2 - m), e3 = __expf(p3 - m);
    if (r1[j] > 0.5f) { e0 *= 1.1f; e1 *= 1.1f; e2 *= 1.1f; e3 *= 2.0f; }
    float inv = 1.f / (e0 + e1 + e2 + e3);
    if (lr16 < 4) {
      float esel = (lr16 == 0) ? e0 : (lr16 == 1) ? e1 : (lr16 == 2) ? e2 : e3;
      alpha_s[(w16 + hi4 * 4 + j) * 4 + lr16] = esel * inv;
    }
  }

  // comb + epilogue: lane = e, rows w16..w16+15 (same wave)
  #pragma unroll 1
  for (int rr = 0; rr < 16; ++rr) {
    int lrow = w16 + rr;
    float4 av = *(const float4*)&alpha_s[lrow * 4];
    int sw = (lrow & 7) << 3, base = lrow * 256;
    float cmb = av.x * bf2f(Hs[(base + lane) ^ sw])
              + av.y * bf2f(Hs[(base + 64 + lane) ^ sw])
              + av.z * bf2f(Hs[(base + 128 + lane) ^ sw])
              + av.w * bf2f(Hs[(base + 192 + lane) ^ sw]);
    size_t row = (size_t)(row0 + lrow);
    size_t gi = row * 64 + lane;
    if (MODE == 0) {
      usig_out[gi] = f2bf(1.f / (1.f + __expf(-cmb)));
    } else if (MODE == 1) {
      candb_out[row * 96 + 32 + lane] = f2bf(cmb * h_prev[gi]);
    } else {
      float u = bf2f(usig_in[gi]), hp = h_prev[gi];
      out_final[gi] = u * tanhf(cmb) + (1.f - u) * hp;
    }
  }
}

// ---------------- host ----------------
extern "C" void kernel_launch(void* const* d_in, const int* in_sizes, int n_in,
                              void* d_out, int out_size, void* d_ws, size_t ws_size,
                              hipStream_t stream) {
  (void)in_sizes; (void)n_in; (void)out_size; (void)ws_size;
  const float* x_t    = (const float*)d_in[0];
  const float* h_prev = (const float*)d_in[1];
  const float* A      = (const float*)d_in[2];
  const float* rs     = (const float*)d_in[3];
  const float* W_u    = (const float*)d_in[4];
  const float* a1w_u  = (const float*)d_in[5];
  const float* a1b_u  = (const float*)d_in[6];
  const float* a2w_u  = (const float*)d_in[7];
  const float* a2b_u  = (const float*)d_in[8];
  const float* W_r    = (const float*)d_in[9];
  const float* a1w_r  = (const float*)d_in[10];
  const float* a1b_r  = (const float*)d_in[11];
  const float* a2w_r  = (const float*)d_in[12];
  const float* a2b_r  = (const float*)d_in[13];
  const float* W_c    = (const float*)d_in[14];
  const float* a1w_c  = (const float*)d_in[15];
  const float* a1b_c  = (const float*)d_in[16];
  const float* a2w_c  = (const float*)d_in[17];
  const float* a2b_c  = (const float*)d_in[18];
  float* out = (float*)d_out;

  char* ws = (char*)d_ws;
  // ws layout (bytes)
  const size_t AN_OFF    = 0;            // 40*1024*1024*2      = 83,886,080
  const size_t DIS_OFF   = 83886080;     // 160,000
  const size_t INPT_OFF  = 84046080;     // 16*96*10048*2       = 30,867,456
  const size_t OUTSU_OFF = 114913536;    // 81,920,000
  const size_t OUTSR_OFF = 196833536;    // max(outsR, hwcT)    = 82,313,216
  const size_t USIG_OFF  = 279146752;    // 20,480,000 (bf16)
  const size_t CANDB_OFF = 299626752;    // 160000*96*2         = 30,720,000
  const size_t WT_OFF    = 330346752;    // 147,456
  const size_t A1WB_OFF  = 330494208;    // 99,072
  const size_t A1WT_OFF  = 330593280;    // 98,304  -> end 330,691,584

  u16* An    = (u16*)(ws + AN_OFF);
  float* dis = (float*)(ws + DIS_OFF);
  u16* inpT  = (u16*)(ws + INPT_OFF);
  u16* outsU = (u16*)(ws + OUTSU_OFF);
  u16* outsR = (u16*)(ws + OUTSR_OFF);
  u16* hwcT  = (u16*)(ws + OUTSR_OFF);   // overlays outsR (dead after attn_R)
  u16* outsC = outsU;                    // overlays outsU (dead after attn_U)
  u16* usig  = (u16*)(ws + USIG_OFF);
  u16* candb = (u16*)(ws + CANDB_OFF);
  u16* Wt    = (u16*)(ws + WT_OFF);
  u16* a1wb  = (u16*)(ws + A1WB_OFF);
  u16* a1wT  = (u16*)(ws + A1WT_OFF);

  prep_weights_kernel<<<674, 256, 0, stream>>>(W_u, W_r, W_c, a1w_u, a1w_r, a1w_c, Wt, a1wb, a1wT);
  rowsum_kernel<<<10000, 256, 0, stream>>>(A, dis);
  build_an_kernel<<<40960, 256, 0, stream>>>(A, dis, An);
  prep_inpT_kernel<<<dim3(157, 16), 256, 0, stream>>>(x_t, h_prev, inpT, candb);

  gemm_uv_kernel<<<dim3(8, 16, 40), 256, 0, stream>>>(An, inpT, Wt, outsU, outsR);

  attn_kernel<0><<<2500, 256, 0, stream>>>(outsU, rs, a1wT, a1wb, a1b_u, a2w_u, a2b_u,
                                           nullptr, nullptr, usig, nullptr, nullptr);
  attn_kernel<1><<<2500, 256, 0, stream>>>(outsR, rs, a1wT + 16384, a1wb + 16512, a1b_r, a2w_r, a2b_r,
                                           h_prev, nullptr, nullptr, candb, nullptr);

  cand_proj_kernel<<<dim3(157, 16), 256, 0, stream>>>(candb, Wt, hwcT);
  gemm_c_kernel<<<dim3(8, 8, 40), 256, 0, stream>>>(An, hwcT, outsC);

  attn_kernel<2><<<2500, 256, 0, stream>>>(outsC, rs, a1wT + 32768, a1wb + 33024, a1b_c, a2w_c, a2b_c,
                                           h_prev, usig, nullptr, nullptr, out);
}